// Round 11
// baseline (506.533 us; speedup 1.0000x reference)
//
#include <hip/hip_runtime.h>
#include <hip/hip_bf16.h>
#include <cstdint>
#include <cstddef>

using bf16 = __hip_bfloat16;

typedef __attribute__((ext_vector_type(4))) float f32x4;
typedef __attribute__((ext_vector_type(8))) short s16x8;

#define LSEQ 4096
#define DDIM 512
#define KFLT 24
#define NFFT 8192
#define MR 8192              // 2*4096 interleaved re/im rows (Nyquist handled rank-1)

__device__ __forceinline__ void gld16(const bf16* g, bf16* l) {
  __builtin_amdgcn_global_load_lds((const __attribute__((address_space(1))) void*)g,
                                   (__attribute__((address_space(3))) void*)l, 16, 0, 0);
}

#define MEMFENCE asm volatile("" ::: "memory")
#define BAR() do { MEMFENCE; __builtin_amdgcn_s_barrier(); MEMFENCE; } while (0)

__device__ __forceinline__ float fsin_rev(float rev) {
  float s; asm("v_sin_f32 %0, %1" : "=v"(s) : "v"(rev)); return s;
}
__device__ __forceinline__ float fcos_rev(float rev) {
  float c; asm("v_cos_f32 %0, %1" : "=v"(c) : "v"(rev)); return c;
}

// Stage one 128x64 bf16 half-tile global->LDS, pre-swizzled source (slot ^= row&7)
__device__ __forceinline__ void stage_half(const bf16* g, int ldk, bf16* ldsbase,
                                           int wave, int lane) {
  const int r8 = lane >> 3;
  const int sc = ((lane & 7) ^ r8) * 8;
  #pragma unroll
  for (int q = 0; q < 2; ++q) {
    const int c = wave * 2 + q;
    gld16(g + (size_t)(c * 8 + r8) * ldk + sc, ldsbase + c * 512);
  }
}

// swizzled LDS fragment read: 16B at slot (kk*4+l4)^(row&7)
__device__ __forceinline__ s16x8 ldfrag(const bf16* buf, int row, int kk, int l4) {
  return *(const s16x8*)(buf + row * 64 + (((kk * 4 + l4) ^ (row & 7)) * 8));
}

// -------- transpose + cast->bf16: out[c][r] = bf16(in[r][c]), batched over z
__global__ __launch_bounds__(256) void transpose_cast(
    const float* __restrict__ in, bf16* __restrict__ out, int R, int C) {
  __shared__ float tile[32][33];
  const size_t bo = (size_t)blockIdx.z * R * C;
  const float* inb = in + bo;
  bf16* outb = out + bo;
  int c0 = blockIdx.x * 32, r0 = blockIdx.y * 32;
  int tx = threadIdx.x & 31, ty = threadIdx.x >> 5;
  #pragma unroll
  for (int i = 0; i < 32; i += 8)
    tile[ty + i][tx] = inb[(size_t)(r0 + ty + i) * C + (c0 + tx)];
  __syncthreads();
  #pragma unroll
  for (int i = 0; i < 32; i += 8)
    outb[(size_t)(c0 + ty + i) * R + (r0 + tx)] = __float2bfloat16(tile[tx][ty + i]);
}

// -------- Auf = bf16(P0 + P1) (two bf16 half-K partials)
__global__ __launch_bounds__(256) void add2_cast(
    const bf16* __restrict__ P, bf16* __restrict__ out) {
  size_t i = ((size_t)blockIdx.x * 256 + threadIdx.x) * 8;
  const size_t MN = (size_t)MR * DDIM;
  s16x8 a = *(const s16x8*)(P + i);
  s16x8 b = *(const s16x8*)(P + i + MN);
  bf16 o[8];
  #pragma unroll
  for (int e = 0; e < 8; ++e) {
    float fa = __uint_as_float((unsigned)(unsigned short)a[e] << 16);
    float fb = __uint_as_float((unsigned)(unsigned short)b[e] << 16);
    o[e] = __float2bfloat16(fa + fb);
  }
  *(s16x8*)(out + i) = *(const s16x8*)o;
}

// -------- Ybt[c][r] = bf16(sum_jg Slot[(jg,nt(c))][r][c&255]); slots [8192][256] f32
__global__ __launch_bounds__(256) void tr_reduce4(
    const float* __restrict__ S, bf16* __restrict__ out) {
  __shared__ float tile[32][33];
  int c0 = blockIdx.x * 32, r0 = blockIdx.y * 32;
  int tx = threadIdx.x & 31, ty = threadIdx.x >> 5;
  const int nt = c0 >> 8;
  const int scl = (c0 & 255) + tx;
  const size_t SB = (size_t)MR * 256;
  #pragma unroll
  for (int i = 0; i < 32; i += 8) {
    size_t ro = (size_t)(r0 + ty + i) * 256 + scl;
    tile[ty + i][tx] = S[(0 * 2 + nt) * SB + ro] + S[(1 * 2 + nt) * SB + ro] +
                       S[(2 * 2 + nt) * SB + ro] + S[(3 * 2 + nt) * SB + ro];
  }
  __syncthreads();
  #pragma unroll
  for (int i = 0; i < 32; i += 8)
    out[(size_t)(c0 + ty + i) * MR + (r0 + tx)] = __float2bfloat16(tile[tx][ty + i]);
}

// -------- y = sum of 4 f32 partials + (-1)^l * vnyq[o] / NFFT
__global__ __launch_bounds__(256) void reduce4y(
    const float* __restrict__ P, const float* __restrict__ vnyq,
    float* __restrict__ y) {
  size_t i = ((size_t)blockIdx.x * 256 + threadIdx.x) * 4;
  const size_t MN = (size_t)LSEQ * DDIM;
  int l = (int)(i >> 9), o = (int)(i & 511);
  f32x4 a = *(const f32x4*)(P + i);
  f32x4 b = *(const f32x4*)(P + i + MN);
  f32x4 c = *(const f32x4*)(P + i + 2 * MN);
  f32x4 d = *(const f32x4*)(P + i + 3 * MN);
  f32x4 v = *(const f32x4*)(vnyq + o);
  float sg = (l & 1) ? -(1.f / NFFT) : (1.f / NFFT);
  f32x4 r = a + b + c + d;
  r[0] += sg * v[0]; r[1] += sg * v[1]; r[2] += sg * v[2]; r[3] += sg * v[3];
  *(f32x4*)(y + i) = r;
}

// -------- Pf[f][k][re,im] f32, f in [0,4096]; 2 f per block (phi reads amortized)
__global__ __launch_bounds__(256) void compute_pf(
    const float* __restrict__ phi, float* __restrict__ Pf) {
  int f0 = blockIdx.x * 2;
  int tid = threadIdx.x;
  int lane = tid & 63, wave = tid >> 6;
  float pre[2][KFLT], pim[2][KFLT];
  #pragma unroll
  for (int ff = 0; ff < 2; ++ff)
    #pragma unroll
    for (int k = 0; k < KFLT; ++k) { pre[ff][k] = 0.f; pim[ff][k] = 0.f; }
  for (int cch = 0; cch < LSEQ / 256; ++cch) {
    int t = cch * 256 + tid;
    const float4* pv = (const float4*)(phi + (size_t)t * KFLT);
    float4 v0 = pv[0], v1 = pv[1], v2 = pv[2], v3 = pv[3], v4 = pv[4], v5 = pv[5];
    float pr[KFLT] = {v0.x, v0.y, v0.z, v0.w, v1.x, v1.y, v1.z, v1.w,
                      v2.x, v2.y, v2.z, v2.w, v3.x, v3.y, v3.z, v3.w,
                      v4.x, v4.y, v4.z, v4.w, v5.x, v5.y, v5.z, v5.w};
    #pragma unroll
    for (int ff = 0; ff < 2; ++ff) {
      int m = ((f0 + ff) * t) & (NFFT - 1);
      float rev = (float)m * (1.f / NFFT);
      float s = fsin_rev(rev), c = fcos_rev(rev);
      #pragma unroll
      for (int k = 0; k < KFLT; ++k) {
        pre[ff][k] += pr[k] * c;
        pim[ff][k] -= pr[k] * s;
      }
    }
  }
  __shared__ float red[4][2][2 * KFLT];
  #pragma unroll
  for (int ff = 0; ff < 2; ++ff)
    #pragma unroll
    for (int k = 0; k < KFLT; ++k) {
      float r = pre[ff][k], i2 = pim[ff][k];
      #pragma unroll
      for (int off = 32; off > 0; off >>= 1) {
        r += __shfl_down(r, off, 64);
        i2 += __shfl_down(i2, off, 64);
      }
      if (lane == 0) { red[wave][ff][2 * k] = r; red[wave][ff][2 * k + 1] = i2; }
    }
  __syncthreads();
  if (tid < 96) {
    int ff = tid / 48, q = tid % 48;
    int f = f0 + ff;
    if (f <= NFFT / 2)
      Pf[(size_t)f * 48 + q] =
          red[0][ff][q] + red[1][ff][q] + red[2][ff][q] + red[3][ff][q];
  }
}

// -------- Pw[j][f][re,im], f in [0,4096); also wnyq[48]
__global__ __launch_bounds__(256) void build_pw(
    const float* __restrict__ Pf, float* __restrict__ Pw, float* __restrict__ wnyq) {
  int idx = blockIdx.x * 256 + threadIdx.x;
  int j = idx >> 12, f = idx & 4095;
  float re, im;
  if (j < KFLT) {
    re = Pf[(size_t)f * 48 + j * 2];
    im = Pf[(size_t)f * 48 + j * 2 + 1];
  } else {
    int k = j - KFLT, g = NFFT / 2 - f;
    re = Pf[(size_t)g * 48 + k * 2];
    im = -Pf[(size_t)g * 48 + k * 2 + 1];
  }
  Pw[(size_t)idx * 2] = re;
  Pw[(size_t)idx * 2 + 1] = im;
  if (idx < 48)
    wnyq[idx] = (idx < KFLT) ? Pf[(size_t)(NFFT / 2) * 48 + idx * 2]
                             : Pf[(idx - KFLT) * 2];
}

// -------- Unyq[d] += partial sum_t (-1)^t u[t][d]  (coalesced, 128 blocks)
__global__ __launch_bounds__(256) void nyq_u(
    const float* __restrict__ u, float* __restrict__ Unyq) {
  int d = blockIdx.x * 256 + threadIdx.x;
  int t0 = blockIdx.y * 64;
  float acc = 0.f;
  for (int t = t0; t < t0 + 64; t += 2)
    acc += u[(size_t)t * DDIM + d] - u[(size_t)(t + 1) * DDIM + d];
  atomicAdd(&Unyq[d], acc);
}

// -------- vnyq[o] += wnyq[j] * sum_d Unyq[d]*Mt[j][o][d]   (grid 48 x 4)
__global__ __launch_bounds__(256) void vnyq_k(
    const bf16* __restrict__ Mt, const float* __restrict__ Unyq,
    const float* __restrict__ wnyq, float* __restrict__ vnyq) {
  __shared__ float us[DDIM];
  int j = blockIdx.x, tid = threadIdx.x;
  us[tid] = Unyq[tid];
  us[tid + 256] = Unyq[tid + 256];
  __syncthreads();
  float w = wnyq[j];
  int o = blockIdx.y * 128 + (tid >> 1);
  int dh = (tid & 1) * 256;
  const bf16* row = Mt + ((size_t)j * DDIM + o) * DDIM + dh;
  float acc = 0.f;
  for (int d0 = 0; d0 < 256; d0 += 8) {
    s16x8 v = *(const s16x8*)(row + d0);
    #pragma unroll
    for (int e = 0; e < 8; ++e)
      acc += us[dh + d0 + e] * __uint_as_float((unsigned)(unsigned short)v[e] << 16);
  }
  acc += __shfl_xor(acc, 1, 64);
  if ((tid & 1) == 0) atomicAdd(&vnyq[o], w * acc);
}

// ======== GEN-GEMM (G1/G3): C = Wgen[M,K] @ Bt[N,K]^T, BM=128 BN=256 BK=64,
// 8 waves 2x4 (wave 64x64), exact-cover 256 blocks, 3-deep LDS.
// A-tile generated in-kernel (trig), swizzled ds_write; B staged via gld16.
template <int STORE>
__global__ __launch_bounds__(512, 2) void gemmG(
    const bf16* __restrict__ Bt, int ldk,
    bf16* __restrict__ Obf, float* __restrict__ Of) {
  __shared__ bf16 sA[3 * 128 * 64];
  __shared__ bf16 sB[3 * 256 * 64];

  const int lin = blockIdx.x;
  const int wid = (lin & 7) * 32 + (lin >> 3);

  int mt, nt, kt0, nkt, ks;
  if constexpr (STORE == 0) {
    ks = wid >> 7; int rem = wid & 127; mt = rem >> 1; nt = rem & 1;
    kt0 = ks * 32; nkt = 32;
  } else {
    ks = wid >> 6; int rem = wid & 63; mt = rem >> 1; nt = rem & 1;
    kt0 = ks * 32; nkt = 32;
  }

  const int tid = threadIdx.x, lane = tid & 63, wave = tid >> 6;
  const int l15 = lane & 15, l4 = lane >> 4;
  const int wr = wave >> 2, wc = wave & 3;
  const int r8 = lane >> 3, c8 = lane & 7;
  const int mtile = mt * 128, ntile = nt * 256;
  const bf16* Bb = Bt + (size_t)ntile * ldk;

  f32x4 acc[4][4];
  #pragma unroll
  for (int m = 0; m < 4; ++m)
    #pragma unroll
    for (int n = 0; n < 4; ++n) acc[m][n] = f32x4{0.f, 0.f, 0.f, 0.f};

  auto genA = [&](int t, int buf) {
    const int kbase = (kt0 + t) * 64 + ((c8 ^ r8) * 8);   // pre-swizzled col base
    #pragma unroll
    for (int q = 0; q < 2; ++q) {
      const int c = wave * 2 + q;
      const int row = mtile + c * 8 + r8;
      bf16 o[8];
      if constexpr (STORE == 0) {
        const int f = row >> 1;
        const bool odd = row & 1;
        #pragma unroll
        for (int e = 0; e < 8; ++e) {
          int m = (f * (kbase + e)) & (NFFT - 1);
          float rev = (float)m * (1.f / NFFT);
          o[e] = __float2bfloat16(odd ? -fsin_rev(rev) : fcos_rev(rev));
        }
      } else {
        #pragma unroll
        for (int e = 0; e < 8; ++e) {
          int r = kbase + e;
          int f = r >> 1;
          int m = (f * row) & (NFFT - 1);
          float rev = (float)m * (1.f / NFFT);
          float sc2 = ((f == 0) ? 1.f : 2.f) * (1.f / NFFT);
          o[e] = __float2bfloat16((r & 1) ? -sc2 * fsin_rev(rev)
                                          : sc2 * fcos_rev(rev));
        }
      }
      *(s16x8*)(sA + buf * (128 * 64) + (c * 8 + r8) * 64 + c8 * 8) =
          *(const s16x8*)o;
    }
  };
  auto stageB = [&](int t, int buf) {
    const size_t ko = (size_t)(kt0 + t) * 64;
    stage_half(Bb + ko, ldk, sB + buf * (256 * 64), wave, lane);
    stage_half(Bb + (size_t)128 * ldk + ko, ldk, sB + buf * (256 * 64) + 128 * 64,
               wave, lane);
  };

  genA(0, 0);
  genA(1, 1);
  stageB(0, 0);
  stageB(1, 1);
  asm volatile("s_waitcnt vmcnt(4)" ::: "memory");
  asm volatile("s_waitcnt lgkmcnt(0)" ::: "memory");
  BAR();

  for (int t = 0; t < nkt; ++t) {
    const int buf = t % 3;
    const bf16* bA = sA + buf * (128 * 64);
    const bf16* bB = sB + buf * (256 * 64);
    const bool i2 = (t + 2 < nkt);

    s16x8 afr[4][2], bfr[4][2];
    #pragma unroll
    for (int n = 0; n < 4; ++n)
      #pragma unroll
      for (int kk = 0; kk < 2; ++kk)
        bfr[n][kk] = ldfrag(bB, wc * 64 + n * 16 + l15, kk, l4);
    #pragma unroll
    for (int m = 0; m < 4; ++m)
      #pragma unroll
      for (int kk = 0; kk < 2; ++kk)
        afr[m][kk] = ldfrag(bA, wr * 64 + m * 16 + l15, kk, l4);

    if (i2) {
      genA(t + 2, (t + 2) % 3);
      stageB(t + 2, (t + 2) % 3);
    }

    __builtin_amdgcn_s_setprio(1);
    #pragma unroll
    for (int m = 0; m < 4; ++m)
      #pragma unroll
      for (int n = 0; n < 4; ++n)
        #pragma unroll
        for (int kk = 0; kk < 2; ++kk)
          acc[m][n] = __builtin_amdgcn_mfma_f32_16x16x32_bf16(
              afr[m][kk], bfr[n][kk], acc[m][n], 0, 0, 0);
    __builtin_amdgcn_s_setprio(0);

    if (i2) { asm volatile("s_waitcnt vmcnt(4)" ::: "memory"); }
    else    { asm volatile("s_waitcnt vmcnt(0)" ::: "memory"); }
    asm volatile("s_waitcnt lgkmcnt(0)" ::: "memory");
    BAR();
  }

  #pragma unroll
  for (int m = 0; m < 4; ++m)
    #pragma unroll
    for (int n = 0; n < 4; ++n)
      #pragma unroll
      for (int e = 0; e < 4; ++e) {
        int row = mtile + wr * 64 + m * 16 + l4 * 4 + e;
        int col = ntile + wc * 64 + n * 16 + l15;
        if constexpr (STORE == 0)
          Obf[(size_t)ks * MR * DDIM + (size_t)row * DDIM + col] =
              __float2bfloat16(acc[m][n][e]);
        else
          Of[(size_t)ks * LSEQ * DDIM + (size_t)row * DDIM + col] = acc[m][n][e];
      }
}

// ======== G2: Slot[(jg,nt)] = sum_{j in jg} Pw[j] .* (Auf @ Mt_j^T).
// REGISTER-RESIDENT A: kt-outer/j-inner; per kt the wave's U-hat fragments live
// in VGPRs (8 int4/thread) reused across 12 j. Per-j A-fragments are built
// IN-REGISTER: row-pair partner via quad_perm DPP (lane^1), then
// wx*self + (+/-wy)*partner, cvt to bf16 — no A LDS round-trip at all.
// B: 3-deep LDS, staged 2-ahead post-barrier, counted vmcnt(4) (0 at tail).
// Pw slice (12KB) + per-kt A tile (32KB) in LDS (lgkm side). 1 barrier/unit.
// Waves 4x2 (wave 64 rows x 128 cols), acc[4][8].
__global__ __launch_bounds__(512, 2) void gemmW(
    const bf16* __restrict__ Auf, const bf16* __restrict__ Mt,
    const float* __restrict__ Pw, float* __restrict__ Slots) {
  __shared__ bf16 sB[3 * 256 * 64];     // 96KB
  __shared__ bf16 sA[256 * 64];         // 32KB (single buffer, kt granularity)
  __shared__ float2 sW[12 * 128];       // 12KB Pw slice [jj][f-local]

  const int lin = blockIdx.x;
  const int q = lin & 7;                // XCD slot (round-robin dispatch)
  const int pos = lin >> 3;             // 0..31 within XCD
  const int jg = q >> 1, mhalf = q & 1;
  const int nt = pos >> 4;
  const int mt = mhalf * 16 + (pos & 15);

  const int tid = threadIdx.x, lane = tid & 63, wave = tid >> 6;
  const int l15 = lane & 15, l4 = lane >> 4;
  const int wr = wave >> 1, wc = wave & 1;   // 4x2 waves: wave = 64 x 128

  float* dst = Slots + (size_t)(jg * 2 + nt) * ((size_t)MR * 256);

  f32x4 acc[4][8];
  #pragma unroll
  for (int m = 0; m < 4; ++m)
    #pragma unroll
    for (int n = 0; n < 8; ++n) acc[m][n] = f32x4{0.f, 0.f, 0.f, 0.f};

  auto stageB_ = [&](int s) {
    const int j = jg * 12 + (s % 12), kt = s / 12;
    const bf16* bb = Mt + (size_t)j * (DDIM * DDIM) + (size_t)(nt * 256) * DDIM + kt * 64;
    bf16* db = sB + (s % 3) * (256 * 64);
    stage_half(bb, DDIM, db, wave, lane);
    stage_half(bb + (size_t)128 * DDIM, DDIM, db + 128 * 64, wave, lane);
  };
  auto stageA_ = [&](int kt) {
    const bf16* ab = Auf + (size_t)(mt * 256) * DDIM + kt * 64;
    stage_half(ab, DDIM, sA, wave, lane);
    stage_half(ab + (size_t)128 * DDIM, DDIM, sA + 128 * 64, wave, lane);
  };

  // ---- prologue: Pw slice -> sW; stage B(0),B(1),A(0); drain once
  #pragma unroll
  for (int t = 0; t < 3; ++t) {
    int idx = tid * 3 + t;                      // 0..1535
    int jj2 = idx >> 7, fo = idx & 127;
    sW[idx] = *(const float2*)(Pw +
        (((size_t)(jg * 12 + jj2)) * 4096 + (size_t)mt * 128 + fo) * 2);
  }
  stageB_(0);
  stageB_(1);
  stageA_(0);
  asm volatile("s_waitcnt vmcnt(0) lgkmcnt(0)" ::: "memory");
  BAR();

  int4 selfA[4][2];                             // [m][kk], per-kt U-hat frags

  for (int s = 0; s < 96; ++s) {
    const int jj = s % 12, kt = s / 12;
    const bf16* bB = sB + (s % 3) * (256 * 64);

    if (s) {
      if (s == 95) { asm volatile("s_waitcnt vmcnt(0)" ::: "memory"); }
      else         { asm volatile("s_waitcnt vmcnt(4)" ::: "memory"); }
      BAR();
    }
    if (s + 2 < 96) stageB_(s + 2);
    if (jj == 6 && kt < 7) stageA_(kt + 1);

    if (jj == 0) {
      #pragma unroll
      for (int m = 0; m < 4; ++m)
        #pragma unroll
        for (int kk = 0; kk < 2; ++kk) {
          s16x8 v = ldfrag(sA, wr * 64 + m * 16 + l15, kk, l4);
          selfA[m][kk] = *(const int4*)&v;
        }
    }

    float wx[4], swy[4];
    #pragma unroll
    for (int m = 0; m < 4; ++m) {
      int fr = (wr * 64 + m * 16 + l15) >> 1;   // local f index 0..127
      float2 w = sW[jj * 128 + fr];
      wx[m] = w.x;
      swy[m] = (l15 & 1) ? w.y : -w.y;
    }

    #pragma unroll
    for (int kk = 0; kk < 2; ++kk) {
      s16x8 bfr[8];
      #pragma unroll
      for (int n = 0; n < 8; ++n)
        bfr[n] = ldfrag(bB, wc * 128 + n * 16 + l15, kk, l4);
      #pragma unroll
      for (int m = 0; m < 4; ++m) {
        const int4 sv = selfA[m][kk];
        int4 pv;
        pv.x = __builtin_amdgcn_mov_dpp(sv.x, 0xB1, 0xF, 0xF, true);  // lane^1
        pv.y = __builtin_amdgcn_mov_dpp(sv.y, 0xB1, 0xF, 0xF, true);
        pv.z = __builtin_amdgcn_mov_dpp(sv.z, 0xB1, 0xF, 0xF, true);
        pv.w = __builtin_amdgcn_mov_dpp(sv.w, 0xB1, 0xF, 0xF, true);
        const int sp[4] = {sv.x, sv.y, sv.z, sv.w};
        const int pp[4] = {pv.x, pv.y, pv.z, pv.w};
        bf16 ob[8];
        #pragma unroll
        for (int t2 = 0; t2 < 4; ++t2) {
          float fsl = __uint_as_float((unsigned)sp[t2] << 16);
          float fsh = __uint_as_float((unsigned)sp[t2] & 0xffff0000u);
          float fpl = __uint_as_float((unsigned)pp[t2] << 16);
          float fph = __uint_as_float((unsigned)pp[t2] & 0xffff0000u);
          ob[2 * t2]     = __float2bfloat16(wx[m] * fsl + swy[m] * fpl);
          ob[2 * t2 + 1] = __float2bfloat16(wx[m] * fsh + swy[m] * fph);
        }
        const s16x8 afr = *(const s16x8*)ob;
        __builtin_amdgcn_s_setprio(1);
        #pragma unroll
        for (int n = 0; n < 8; ++n)
          acc[m][n] = __builtin_amdgcn_mfma_f32_16x16x32_bf16(
              afr, bfr[n], acc[m][n], 0, 0, 0);
        __builtin_amdgcn_s_setprio(0);
      }
    }
  }

  // single flush into the block's private (mt, nt) slot region
  #pragma unroll
  for (int m = 0; m < 4; ++m)
    #pragma unroll
    for (int n = 0; n < 8; ++n)
      #pragma unroll
      for (int e = 0; e < 4; ++e) {
        int row = mt * 256 + wr * 64 + m * 16 + l4 * 4 + e;
        int col = wc * 128 + n * 16 + l15;
        dst[(size_t)row * 256 + col] = acc[m][n][e];
      }
}

// ---------------- workspace layout (bytes) ----------------
#define WS_W     0ULL                    // 67,108,864: G2 slots (8 x [8192][256] f32)
#define WS_AUF   67108864ULL             // 8192x512 bf16 = 8,388,608 (later G3P start)
#define WS_UT    75497472ULL             // 512x4096 bf16 = 4,194,304
#define WS_MT    79691776ULL             // 48x512x512 bf16 = 25,165,824
#define WS_PF    104857600ULL            // 4097x48 f32
#define WS_PW    105644288ULL            // 48x4096x2 f32 = 1,572,864
#define WS_WNYQ  107217152ULL            // 48 f32
#define WS_UNYQ  107217408ULL            // 512 f32
#define WS_VNYQ  107219456ULL            // 512 f32
#define WS_YBT   107221504ULL            // 512x8192 bf16 = 8,388,608
#define WS_G1P   115610112ULL            // 2 x 8192x512 bf16 = 16,777,216
#define WS_TOTAL 132387328ULL
// G3 partials: 4 x 4096x512 f32 = 33,554,432 at WS_AUF (Auf/uT/Mt dead by G3)

extern "C" void kernel_launch(void* const* d_in, const int* in_sizes, int n_in,
                              void* d_out, int out_size, void* d_ws, size_t ws_size,
                              hipStream_t stream) {
  const float* u   = (const float*)d_in[0];   // [4096, 512]
  const float* phi = (const float*)d_in[1];   // [4096, 24]
  const float* Mp  = (const float*)d_in[2];   // [24, 512, 512]
  const float* Mm  = (const float*)d_in[3];   // [24, 512, 512]
  float* y = (float*)d_out;                   // [4096, 512]

  if (ws_size < WS_TOTAL) return;             // loud failure: output stays zero

  char* ws = (char*)d_ws;
  float* Slots= (float*)(ws + WS_W);
  bf16*  Auf  = (bf16*)(ws + WS_AUF);
  bf16*  uT   = (bf16*)(ws + WS_UT);
  bf16*  Mt   = (bf16*)(ws + WS_MT);
  float* Pf   = (float*)(ws + WS_PF);
  float* Pw   = (float*)(ws + WS_PW);
  float* wny  = (float*)(ws + WS_WNYQ);
  float* Uny  = (float*)(ws + WS_UNYQ);
  float* vny  = (float*)(ws + WS_VNYQ);
  bf16*  Ybt  = (bf16*)(ws + WS_YBT);
  bf16*  G1P  = (bf16*)(ws + WS_G1P);
  float* G3P  = (float*)(ws + WS_AUF);        // G3 partials overlay

  // prologue (no W/Cinv materialization — generated inside gemmG)
  transpose_cast<<<dim3(16, 128, 1), 256, 0, stream>>>(u, uT, LSEQ, DDIM);
  transpose_cast<<<dim3(16, 16, 24), 256, 0, stream>>>(Mp, Mt, DDIM, DDIM);
  transpose_cast<<<dim3(16, 16, 24), 256, 0, stream>>>(Mm, Mt + (size_t)24 * DDIM * DDIM,
                                                       DDIM, DDIM);
  compute_pf<<<dim3(2049), 256, 0, stream>>>(phi, Pf);
  build_pw<<<dim3(48 * 4096 / 256), 256, 0, stream>>>(Pf, Pw, wny);
  hipMemsetAsync(Uny, 0, DDIM * sizeof(float), stream);
  nyq_u<<<dim3(2, 64), 256, 0, stream>>>(u, Uny);

  // G1: Auf = bf16(Wdft_gen @ u), 256 blocks, ks2 bf16 partials + add-cast
  gemmG<0><<<256, 512, 0, stream>>>(uT, LSEQ, G1P, nullptr);
  add2_cast<<<dim3(MR * DDIM / 2048), 256, 0, stream>>>(G1P, Auf);

  // G2: 8 XCD-combo slots (full coverage, no memset)
  gemmW<<<256, 512, 0, stream>>>(Auf, Mt, Pw, Slots);

  // Ybt = bf16((sum of 4 jg-slots)^T); Nyquist vector (needs Mt) before G3
  tr_reduce4<<<dim3(16, 256), 256, 0, stream>>>(Slots, Ybt);
  hipMemsetAsync(vny, 0, DDIM * sizeof(float), stream);
  vnyq_k<<<dim3(48, 4), 256, 0, stream>>>(Mt, Uny, wny, vny);

  // G3: y = Cinv_gen @ Ysum via 4 f32 ksplit partials + fused Nyquist reduce
  gemmG<1><<<256, 512, 0, stream>>>(Ybt, MR, nullptr, G3P);
  reduce4y<<<dim3(LSEQ * DDIM / 1024), 256, 0, stream>>>(G3P, vny, y);
}

// Round 12
// 484.254 us; speedup vs baseline: 1.0460x; 1.0460x over previous
//
#include <hip/hip_runtime.h>
#include <hip/hip_bf16.h>
#include <cstdint>
#include <cstddef>

using bf16 = __hip_bfloat16;

typedef __attribute__((ext_vector_type(4))) float f32x4;
typedef __attribute__((ext_vector_type(8))) short s16x8;

#define LSEQ 4096
#define DDIM 512
#define KFLT 24
#define NFFT 8192
#define MR 8192              // 2*4096 interleaved re/im rows (Nyquist handled rank-1)

__device__ __forceinline__ void gld16(const bf16* g, bf16* l) {
  __builtin_amdgcn_global_load_lds((const __attribute__((address_space(1))) void*)g,
                                   (__attribute__((address_space(3))) void*)l, 16, 0, 0);
}

#define MEMFENCE asm volatile("" ::: "memory")
#define BAR() do { MEMFENCE; __builtin_amdgcn_s_barrier(); MEMFENCE; } while (0)

__device__ __forceinline__ float fsin_rev(float rev) {
  float s; asm("v_sin_f32 %0, %1" : "=v"(s) : "v"(rev)); return s;
}
__device__ __forceinline__ float fcos_rev(float rev) {
  float c; asm("v_cos_f32 %0, %1" : "=v"(c) : "v"(rev)); return c;
}

// Stage one 128x64 bf16 half-tile global->LDS, 8 waves x 2 chunks (512-thr blocks)
__device__ __forceinline__ void stage_half(const bf16* g, int ldk, bf16* ldsbase,
                                           int wave, int lane) {
  const int r8 = lane >> 3;
  const int sc = ((lane & 7) ^ r8) * 8;
  #pragma unroll
  for (int q = 0; q < 2; ++q) {
    const int c = wave * 2 + q;
    gld16(g + (size_t)(c * 8 + r8) * ldk + sc, ldsbase + c * 512);
  }
}

// Stage one 128x64 half-tile with 16 waves x 1 chunk (1024-thr blocks)
__device__ __forceinline__ void stage16(const bf16* g, int ldk, bf16* ldsbase,
                                        int wave, int lane) {
  const int r8 = lane >> 3;
  const int sc = ((lane & 7) ^ r8) * 8;
  gld16(g + (size_t)(wave * 8 + r8) * ldk + sc, ldsbase + wave * 512);
}

// swizzled LDS fragment read: 16B at slot (kk*4+l4)^(row&7)
__device__ __forceinline__ s16x8 ldfrag(const bf16* buf, int row, int kk, int l4) {
  return *(const s16x8*)(buf + row * 64 + (((kk * 4 + l4) ^ (row & 7)) * 8));
}

// -------- transpose + cast->bf16: out[c][r] = bf16(in[r][c]), batched over z
__global__ __launch_bounds__(256) void transpose_cast(
    const float* __restrict__ in, bf16* __restrict__ out, int R, int C) {
  __shared__ float tile[32][33];
  const size_t bo = (size_t)blockIdx.z * R * C;
  const float* inb = in + bo;
  bf16* outb = out + bo;
  int c0 = blockIdx.x * 32, r0 = blockIdx.y * 32;
  int tx = threadIdx.x & 31, ty = threadIdx.x >> 5;
  #pragma unroll
  for (int i = 0; i < 32; i += 8)
    tile[ty + i][tx] = inb[(size_t)(r0 + ty + i) * C + (c0 + tx)];
  __syncthreads();
  #pragma unroll
  for (int i = 0; i < 32; i += 8)
    outb[(size_t)(c0 + ty + i) * R + (r0 + tx)] = __float2bfloat16(tile[tx][ty + i]);
}

// -------- Auf = bf16(P0 + P1) (two bf16 half-K partials)
__global__ __launch_bounds__(256) void add2_cast(
    const bf16* __restrict__ P, bf16* __restrict__ out) {
  size_t i = ((size_t)blockIdx.x * 256 + threadIdx.x) * 8;
  const size_t MN = (size_t)MR * DDIM;
  s16x8 a = *(const s16x8*)(P + i);
  s16x8 b = *(const s16x8*)(P + i + MN);
  bf16 o[8];
  #pragma unroll
  for (int e = 0; e < 8; ++e) {
    float fa = __uint_as_float((unsigned)(unsigned short)a[e] << 16);
    float fb = __uint_as_float((unsigned)(unsigned short)b[e] << 16);
    o[e] = __float2bfloat16(fa + fb);
  }
  *(s16x8*)(out + i) = *(const s16x8*)o;
}

// -------- Ybt[c][r] = bf16(sum_jg Slot[(jg,nt(c))][r][c&255]); slots [8192][256] f32
__global__ __launch_bounds__(256) void tr_reduce4(
    const float* __restrict__ S, bf16* __restrict__ out) {
  __shared__ float tile[32][33];
  int c0 = blockIdx.x * 32, r0 = blockIdx.y * 32;
  int tx = threadIdx.x & 31, ty = threadIdx.x >> 5;
  const int nt = c0 >> 8;
  const int scl = (c0 & 255) + tx;
  const size_t SB = (size_t)MR * 256;
  #pragma unroll
  for (int i = 0; i < 32; i += 8) {
    size_t ro = (size_t)(r0 + ty + i) * 256 + scl;
    tile[ty + i][tx] = S[(0 * 2 + nt) * SB + ro] + S[(1 * 2 + nt) * SB + ro] +
                       S[(2 * 2 + nt) * SB + ro] + S[(3 * 2 + nt) * SB + ro];
  }
  __syncthreads();
  #pragma unroll
  for (int i = 0; i < 32; i += 8)
    out[(size_t)(c0 + ty + i) * MR + (r0 + tx)] = __float2bfloat16(tile[tx][ty + i]);
}

// -------- y = sum of 4 f32 partials + (-1)^l * vnyq[o] / NFFT
__global__ __launch_bounds__(256) void reduce4y(
    const float* __restrict__ P, const float* __restrict__ vnyq,
    float* __restrict__ y) {
  size_t i = ((size_t)blockIdx.x * 256 + threadIdx.x) * 4;
  const size_t MN = (size_t)LSEQ * DDIM;
  int l = (int)(i >> 9), o = (int)(i & 511);
  f32x4 a = *(const f32x4*)(P + i);
  f32x4 b = *(const f32x4*)(P + i + MN);
  f32x4 c = *(const f32x4*)(P + i + 2 * MN);
  f32x4 d = *(const f32x4*)(P + i + 3 * MN);
  f32x4 v = *(const f32x4*)(vnyq + o);
  float sg = (l & 1) ? -(1.f / NFFT) : (1.f / NFFT);
  f32x4 r = a + b + c + d;
  r[0] += sg * v[0]; r[1] += sg * v[1]; r[2] += sg * v[2]; r[3] += sg * v[3];
  *(f32x4*)(y + i) = r;
}

// -------- Pf[f][k][re,im] f32, f in [0,4096]; 2 f per block (phi reads amortized)
__global__ __launch_bounds__(256) void compute_pf(
    const float* __restrict__ phi, float* __restrict__ Pf) {
  int f0 = blockIdx.x * 2;
  int tid = threadIdx.x;
  int lane = tid & 63, wave = tid >> 6;
  float pre[2][KFLT], pim[2][KFLT];
  #pragma unroll
  for (int ff = 0; ff < 2; ++ff)
    #pragma unroll
    for (int k = 0; k < KFLT; ++k) { pre[ff][k] = 0.f; pim[ff][k] = 0.f; }
  for (int cch = 0; cch < LSEQ / 256; ++cch) {
    int t = cch * 256 + tid;
    const float4* pv = (const float4*)(phi + (size_t)t * KFLT);
    float4 v0 = pv[0], v1 = pv[1], v2 = pv[2], v3 = pv[3], v4 = pv[4], v5 = pv[5];
    float pr[KFLT] = {v0.x, v0.y, v0.z, v0.w, v1.x, v1.y, v1.z, v1.w,
                      v2.x, v2.y, v2.z, v2.w, v3.x, v3.y, v3.z, v3.w,
                      v4.x, v4.y, v4.z, v4.w, v5.x, v5.y, v5.z, v5.w};
    #pragma unroll
    for (int ff = 0; ff < 2; ++ff) {
      int m = ((f0 + ff) * t) & (NFFT - 1);
      float rev = (float)m * (1.f / NFFT);
      float s = fsin_rev(rev), c = fcos_rev(rev);
      #pragma unroll
      for (int k = 0; k < KFLT; ++k) {
        pre[ff][k] += pr[k] * c;
        pim[ff][k] -= pr[k] * s;
      }
    }
  }
  __shared__ float red[4][2][2 * KFLT];
  #pragma unroll
  for (int ff = 0; ff < 2; ++ff)
    #pragma unroll
    for (int k = 0; k < KFLT; ++k) {
      float r = pre[ff][k], i2 = pim[ff][k];
      #pragma unroll
      for (int off = 32; off > 0; off >>= 1) {
        r += __shfl_down(r, off, 64);
        i2 += __shfl_down(i2, off, 64);
      }
      if (lane == 0) { red[wave][ff][2 * k] = r; red[wave][ff][2 * k + 1] = i2; }
    }
  __syncthreads();
  if (tid < 96) {
    int ff = tid / 48, q = tid % 48;
    int f = f0 + ff;
    if (f <= NFFT / 2)
      Pf[(size_t)f * 48 + q] =
          red[0][ff][q] + red[1][ff][q] + red[2][ff][q] + red[3][ff][q];
  }
}

// -------- Pw[j][f][re,im], f in [0,4096); also wnyq[48]
__global__ __launch_bounds__(256) void build_pw(
    const float* __restrict__ Pf, float* __restrict__ Pw, float* __restrict__ wnyq) {
  int idx = blockIdx.x * 256 + threadIdx.x;
  int j = idx >> 12, f = idx & 4095;
  float re, im;
  if (j < KFLT) {
    re = Pf[(size_t)f * 48 + j * 2];
    im = Pf[(size_t)f * 48 + j * 2 + 1];
  } else {
    int k = j - KFLT, g = NFFT / 2 - f;
    re = Pf[(size_t)g * 48 + k * 2];
    im = -Pf[(size_t)g * 48 + k * 2 + 1];
  }
  Pw[(size_t)idx * 2] = re;
  Pw[(size_t)idx * 2 + 1] = im;
  if (idx < 48)
    wnyq[idx] = (idx < KFLT) ? Pf[(size_t)(NFFT / 2) * 48 + idx * 2]
                             : Pf[(idx - KFLT) * 2];
}

// -------- Unyq[d] += partial sum_t (-1)^t u[t][d]  (coalesced, 128 blocks)
__global__ __launch_bounds__(256) void nyq_u(
    const float* __restrict__ u, float* __restrict__ Unyq) {
  int d = blockIdx.x * 256 + threadIdx.x;
  int t0 = blockIdx.y * 64;
  float acc = 0.f;
  for (int t = t0; t < t0 + 64; t += 2)
    acc += u[(size_t)t * DDIM + d] - u[(size_t)(t + 1) * DDIM + d];
  atomicAdd(&Unyq[d], acc);
}

// -------- vnyq[o] += wnyq[j] * sum_d Unyq[d]*Mt[j][o][d]   (grid 48 x 4)
__global__ __launch_bounds__(256) void vnyq_k(
    const bf16* __restrict__ Mt, const float* __restrict__ Unyq,
    const float* __restrict__ wnyq, float* __restrict__ vnyq) {
  __shared__ float us[DDIM];
  int j = blockIdx.x, tid = threadIdx.x;
  us[tid] = Unyq[tid];
  us[tid + 256] = Unyq[tid + 256];
  __syncthreads();
  float w = wnyq[j];
  int o = blockIdx.y * 128 + (tid >> 1);
  int dh = (tid & 1) * 256;
  const bf16* row = Mt + ((size_t)j * DDIM + o) * DDIM + dh;
  float acc = 0.f;
  for (int d0 = 0; d0 < 256; d0 += 8) {
    s16x8 v = *(const s16x8*)(row + d0);
    #pragma unroll
    for (int e = 0; e < 8; ++e)
      acc += us[dh + d0 + e] * __uint_as_float((unsigned)(unsigned short)v[e] << 16);
  }
  acc += __shfl_xor(acc, 1, 64);
  if ((tid & 1) == 0) atomicAdd(&vnyq[o], w * acc);
}

// ======== GEN-GEMM (G1/G3): C = Wgen[M,K] @ Bt[N,K]^T, BM=128 BN=256 BK=64,
// 8 waves 2x4 (wave 64x64), exact-cover 256 blocks, 3-deep LDS.
// A-tile generated in-kernel (trig), swizzled ds_write; B staged via gld16.
template <int STORE>
__global__ __launch_bounds__(512, 2) void gemmG(
    const bf16* __restrict__ Bt, int ldk,
    bf16* __restrict__ Obf, float* __restrict__ Of) {
  __shared__ bf16 sA[3 * 128 * 64];
  __shared__ bf16 sB[3 * 256 * 64];

  const int lin = blockIdx.x;
  const int wid = (lin & 7) * 32 + (lin >> 3);

  int mt, nt, kt0, nkt, ks;
  if constexpr (STORE == 0) {
    ks = wid >> 7; int rem = wid & 127; mt = rem >> 1; nt = rem & 1;
    kt0 = ks * 32; nkt = 32;
  } else {
    ks = wid >> 6; int rem = wid & 63; mt = rem >> 1; nt = rem & 1;
    kt0 = ks * 32; nkt = 32;
  }

  const int tid = threadIdx.x, lane = tid & 63, wave = tid >> 6;
  const int l15 = lane & 15, l4 = lane >> 4;
  const int wr = wave >> 2, wc = wave & 3;
  const int r8 = lane >> 3, c8 = lane & 7;
  const int mtile = mt * 128, ntile = nt * 256;
  const bf16* Bb = Bt + (size_t)ntile * ldk;

  f32x4 acc[4][4];
  #pragma unroll
  for (int m = 0; m < 4; ++m)
    #pragma unroll
    for (int n = 0; n < 4; ++n) acc[m][n] = f32x4{0.f, 0.f, 0.f, 0.f};

  auto genA = [&](int t, int buf) {
    const int kbase = (kt0 + t) * 64 + ((c8 ^ r8) * 8);   // pre-swizzled col base
    #pragma unroll
    for (int q = 0; q < 2; ++q) {
      const int c = wave * 2 + q;
      const int row = mtile + c * 8 + r8;
      bf16 o[8];
      if constexpr (STORE == 0) {
        const int f = row >> 1;
        const bool odd = row & 1;
        #pragma unroll
        for (int e = 0; e < 8; ++e) {
          int m = (f * (kbase + e)) & (NFFT - 1);
          float rev = (float)m * (1.f / NFFT);
          o[e] = __float2bfloat16(odd ? -fsin_rev(rev) : fcos_rev(rev));
        }
      } else {
        #pragma unroll
        for (int e = 0; e < 8; ++e) {
          int r = kbase + e;
          int f = r >> 1;
          int m = (f * row) & (NFFT - 1);
          float rev = (float)m * (1.f / NFFT);
          float sc2 = ((f == 0) ? 1.f : 2.f) * (1.f / NFFT);
          o[e] = __float2bfloat16((r & 1) ? -sc2 * fsin_rev(rev)
                                          : sc2 * fcos_rev(rev));
        }
      }
      *(s16x8*)(sA + buf * (128 * 64) + (c * 8 + r8) * 64 + c8 * 8) =
          *(const s16x8*)o;
    }
  };
  auto stageB = [&](int t, int buf) {
    const size_t ko = (size_t)(kt0 + t) * 64;
    stage_half(Bb + ko, ldk, sB + buf * (256 * 64), wave, lane);
    stage_half(Bb + (size_t)128 * ldk + ko, ldk, sB + buf * (256 * 64) + 128 * 64,
               wave, lane);
  };

  genA(0, 0);
  genA(1, 1);
  stageB(0, 0);
  stageB(1, 1);
  asm volatile("s_waitcnt vmcnt(4)" ::: "memory");
  asm volatile("s_waitcnt lgkmcnt(0)" ::: "memory");
  BAR();

  for (int t = 0; t < nkt; ++t) {
    const int buf = t % 3;
    const bf16* bA = sA + buf * (128 * 64);
    const bf16* bB = sB + buf * (256 * 64);
    const bool i2 = (t + 2 < nkt);

    s16x8 afr[4][2], bfr[4][2];
    #pragma unroll
    for (int n = 0; n < 4; ++n)
      #pragma unroll
      for (int kk = 0; kk < 2; ++kk)
        bfr[n][kk] = ldfrag(bB, wc * 64 + n * 16 + l15, kk, l4);
    #pragma unroll
    for (int m = 0; m < 4; ++m)
      #pragma unroll
      for (int kk = 0; kk < 2; ++kk)
        afr[m][kk] = ldfrag(bA, wr * 64 + m * 16 + l15, kk, l4);

    if (i2) {
      genA(t + 2, (t + 2) % 3);
      stageB(t + 2, (t + 2) % 3);
    }

    __builtin_amdgcn_s_setprio(1);
    #pragma unroll
    for (int m = 0; m < 4; ++m)
      #pragma unroll
      for (int n = 0; n < 4; ++n)
        #pragma unroll
        for (int kk = 0; kk < 2; ++kk)
          acc[m][n] = __builtin_amdgcn_mfma_f32_16x16x32_bf16(
              afr[m][kk], bfr[n][kk], acc[m][n], 0, 0, 0);
    __builtin_amdgcn_s_setprio(0);

    if (i2) { asm volatile("s_waitcnt vmcnt(4)" ::: "memory"); }
    else    { asm volatile("s_waitcnt vmcnt(0)" ::: "memory"); }
    asm volatile("s_waitcnt lgkmcnt(0)" ::: "memory");
    BAR();
  }

  #pragma unroll
  for (int m = 0; m < 4; ++m)
    #pragma unroll
    for (int n = 0; n < 4; ++n)
      #pragma unroll
      for (int e = 0; e < 4; ++e) {
        int row = mtile + wr * 64 + m * 16 + l4 * 4 + e;
        int col = ntile + wc * 64 + n * 16 + l15;
        if constexpr (STORE == 0)
          Obf[(size_t)ks * MR * DDIM + (size_t)row * DDIM + col] =
              __float2bfloat16(acc[m][n][e]);
        else
          Of[(size_t)ks * LSEQ * DDIM + (size_t)row * DDIM + col] = acc[m][n][e];
      }
}

// ======== G2: Slot[(jg,nt)] = sum_{j in jg} Pw[j] .* (Auf @ Mt_j^T).
// 16-WAVE OCCUPANCY BUILD: 1024 threads (4 waves/SIMD), wave = 32x128
// (acc[2][8]=64 regs, launch_bounds cap 128 -> double wave residency vs R11).
// Register-resident A per kt (selfA from sA LDS tile, reused across 12 j);
// per-j A-frags built in-register via quad_perm DPP row-pair mix. B: 3-deep
// LDS, staged 2-ahead, counted vmcnt(2); 1 barrier/unit. Same MFMA order as
// R11 -> bit-identical output.
__global__ __launch_bounds__(1024, 4) void gemmW(
    const bf16* __restrict__ Auf, const bf16* __restrict__ Mt,
    const float* __restrict__ Pw, float* __restrict__ Slots) {
  __shared__ bf16 sB[3 * 256 * 64];     // 96KB
  __shared__ bf16 sA[256 * 64];         // 32KB (single buffer, kt granularity)
  __shared__ float2 sW[12 * 128];       // 12KB Pw slice [jj][f-local]

  const int lin = blockIdx.x;
  const int q = lin & 7;                // XCD slot (round-robin dispatch)
  const int pos = lin >> 3;             // 0..31 within XCD
  const int jg = q >> 1, mhalf = q & 1;
  const int nt = pos >> 4;
  const int mt = mhalf * 16 + (pos & 15);

  const int tid = threadIdx.x, lane = tid & 63, wave = tid >> 6;  // 0..15
  const int l15 = lane & 15, l4 = lane >> 4;
  const int wr = wave >> 1, wc = wave & 1;   // 8x2 waves: wave = 32 x 128

  float* dst = Slots + (size_t)(jg * 2 + nt) * ((size_t)MR * 256);

  f32x4 acc[2][8];
  #pragma unroll
  for (int m = 0; m < 2; ++m)
    #pragma unroll
    for (int n = 0; n < 8; ++n) acc[m][n] = f32x4{0.f, 0.f, 0.f, 0.f};

  auto stageB_ = [&](int s) {
    const int j = jg * 12 + (s % 12), kt = s / 12;
    const bf16* bb = Mt + (size_t)j * (DDIM * DDIM) + (size_t)(nt * 256) * DDIM + kt * 64;
    bf16* db = sB + (s % 3) * (256 * 64);
    stage16(bb, DDIM, db, wave, lane);
    stage16(bb + (size_t)128 * DDIM, DDIM, db + 128 * 64, wave, lane);
  };
  auto stageA_ = [&](int kt) {
    const bf16* ab = Auf + (size_t)(mt * 256) * DDIM + kt * 64;
    stage16(ab, DDIM, sA, wave, lane);
    stage16(ab + (size_t)128 * DDIM, DDIM, sA + 128 * 64, wave, lane);
  };

  // ---- prologue: Pw slice -> sW; stage B(0),B(1),A(0); drain once
  for (int idx = tid; idx < 1536; idx += 1024) {
    int jj2 = idx >> 7, fo = idx & 127;
    sW[idx] = *(const float2*)(Pw +
        (((size_t)(jg * 12 + jj2)) * 4096 + (size_t)mt * 128 + fo) * 2);
  }
  stageB_(0);
  stageB_(1);
  stageA_(0);
  asm volatile("s_waitcnt vmcnt(0) lgkmcnt(0)" ::: "memory");
  BAR();

  int4 selfA[2][2];                             // [m][kk], per-kt U-hat frags

  for (int s = 0; s < 96; ++s) {
    const int jj = s % 12, kt = s / 12;
    const bf16* bB = sB + (s % 3) * (256 * 64);

    if (s) {
      if (s == 95) { asm volatile("s_waitcnt vmcnt(0)" ::: "memory"); }
      else         { asm volatile("s_waitcnt vmcnt(2)" ::: "memory"); }
      BAR();
    }
    if (s + 2 < 96) stageB_(s + 2);
    if (jj == 6 && kt < 7) stageA_(kt + 1);

    if (jj == 0) {
      #pragma unroll
      for (int m = 0; m < 2; ++m)
        #pragma unroll
        for (int kk = 0; kk < 2; ++kk) {
          s16x8 v = ldfrag(sA, wr * 32 + m * 16 + l15, kk, l4);
          selfA[m][kk] = *(const int4*)&v;
        }
    }

    float wx[2], swy[2];
    #pragma unroll
    for (int m = 0; m < 2; ++m) {
      int fr = (wr * 32 + m * 16 + l15) >> 1;   // local f index 0..127
      float2 w = sW[jj * 128 + fr];
      wx[m] = w.x;
      swy[m] = (l15 & 1) ? w.y : -w.y;
    }

    #pragma unroll
    for (int kk = 0; kk < 2; ++kk) {
      // build both A-frags for this kk (in-register complex mix)
      s16x8 afr[2];
      #pragma unroll
      for (int m = 0; m < 2; ++m) {
        const int4 sv = selfA[m][kk];
        int4 pv;
        pv.x = __builtin_amdgcn_mov_dpp(sv.x, 0xB1, 0xF, 0xF, true);  // lane^1
        pv.y = __builtin_amdgcn_mov_dpp(sv.y, 0xB1, 0xF, 0xF, true);
        pv.z = __builtin_amdgcn_mov_dpp(sv.z, 0xB1, 0xF, 0xF, true);
        pv.w = __builtin_amdgcn_mov_dpp(sv.w, 0xB1, 0xF, 0xF, true);
        const int sp[4] = {sv.x, sv.y, sv.z, sv.w};
        const int pp[4] = {pv.x, pv.y, pv.z, pv.w};
        bf16 ob[8];
        #pragma unroll
        for (int t2 = 0; t2 < 4; ++t2) {
          float fsl = __uint_as_float((unsigned)sp[t2] << 16);
          float fsh = __uint_as_float((unsigned)sp[t2] & 0xffff0000u);
          float fpl = __uint_as_float((unsigned)pp[t2] << 16);
          float fph = __uint_as_float((unsigned)pp[t2] & 0xffff0000u);
          ob[2 * t2]     = __float2bfloat16(wx[m] * fsl + swy[m] * fpl);
          ob[2 * t2 + 1] = __float2bfloat16(wx[m] * fsh + swy[m] * fph);
        }
        afr[m] = *(const s16x8*)ob;
      }
      // n split in two halves keeps live bfr regs at 4 x s16x8
      #pragma unroll
      for (int nh = 0; nh < 2; ++nh) {
        s16x8 bfr[4];
        #pragma unroll
        for (int n = 0; n < 4; ++n)
          bfr[n] = ldfrag(bB, wc * 128 + (nh * 4 + n) * 16 + l15, kk, l4);
        __builtin_amdgcn_s_setprio(1);
        #pragma unroll
        for (int m = 0; m < 2; ++m)
          #pragma unroll
          for (int n = 0; n < 4; ++n)
            acc[m][nh * 4 + n] = __builtin_amdgcn_mfma_f32_16x16x32_bf16(
                afr[m], bfr[n], acc[m][nh * 4 + n], 0, 0, 0);
        __builtin_amdgcn_s_setprio(0);
      }
    }
  }

  // single flush into the block's private (mt, nt) slot region
  #pragma unroll
  for (int m = 0; m < 2; ++m)
    #pragma unroll
    for (int n = 0; n < 8; ++n)
      #pragma unroll
      for (int e = 0; e < 4; ++e) {
        int row = mt * 256 + wr * 32 + m * 16 + l4 * 4 + e;
        int col = wc * 128 + n * 16 + l15;
        dst[(size_t)row * 256 + col] = acc[m][n][e];
      }
}

// ---------------- workspace layout (bytes) ----------------
#define WS_W     0ULL                    // 67,108,864: G2 slots (8 x [8192][256] f32)
#define WS_AUF   67108864ULL             // 8192x512 bf16 = 8,388,608 (later G3P start)
#define WS_UT    75497472ULL             // 512x4096 bf16 = 4,194,304
#define WS_MT    79691776ULL             // 48x512x512 bf16 = 25,165,824
#define WS_PF    104857600ULL            // 4097x48 f32
#define WS_PW    105644288ULL            // 48x4096x2 f32 = 1,572,864
#define WS_WNYQ  107217152ULL            // 48 f32
#define WS_UNYQ  107217408ULL            // 512 f32
#define WS_VNYQ  107219456ULL            // 512 f32
#define WS_YBT   107221504ULL            // 512x8192 bf16 = 8,388,608
#define WS_G1P   115610112ULL            // 2 x 8192x512 bf16 = 16,777,216
#define WS_TOTAL 132387328ULL
// G3 partials: 4 x 4096x512 f32 = 33,554,432 at WS_AUF (Auf/uT/Mt dead by G3)

extern "C" void kernel_launch(void* const* d_in, const int* in_sizes, int n_in,
                              void* d_out, int out_size, void* d_ws, size_t ws_size,
                              hipStream_t stream) {
  const float* u   = (const float*)d_in[0];   // [4096, 512]
  const float* phi = (const float*)d_in[1];   // [4096, 24]
  const float* Mp  = (const float*)d_in[2];   // [24, 512, 512]
  const float* Mm  = (const float*)d_in[3];   // [24, 512, 512]
  float* y = (float*)d_out;                   // [4096, 512]

  if (ws_size < WS_TOTAL) return;             // loud failure: output stays zero

  char* ws = (char*)d_ws;
  float* Slots= (float*)(ws + WS_W);
  bf16*  Auf  = (bf16*)(ws + WS_AUF);
  bf16*  uT   = (bf16*)(ws + WS_UT);
  bf16*  Mt   = (bf16*)(ws + WS_MT);
  float* Pf   = (float*)(ws + WS_PF);
  float* Pw   = (float*)(ws + WS_PW);
  float* wny  = (float*)(ws + WS_WNYQ);
  float* Uny  = (float*)(ws + WS_UNYQ);
  float* vny  = (float*)(ws + WS_VNYQ);
  bf16*  Ybt  = (bf16*)(ws + WS_YBT);
  bf16*  G1P  = (bf16*)(ws + WS_G1P);
  float* G3P  = (float*)(ws + WS_AUF);        // G3 partials overlay

  // prologue (no W/Cinv materialization — generated inside gemmG)
  transpose_cast<<<dim3(16, 128, 1), 256, 0, stream>>>(u, uT, LSEQ, DDIM);
  transpose_cast<<<dim3(16, 16, 24), 256, 0, stream>>>(Mp, Mt, DDIM, DDIM);
  transpose_cast<<<dim3(16, 16, 24), 256, 0, stream>>>(Mm, Mt + (size_t)24 * DDIM * DDIM,
                                                       DDIM, DDIM);
  compute_pf<<<dim3(2049), 256, 0, stream>>>(phi, Pf);
  build_pw<<<dim3(48 * 4096 / 256), 256, 0, stream>>>(Pf, Pw, wny);
  hipMemsetAsync(Uny, 0, DDIM * sizeof(float), stream);
  nyq_u<<<dim3(2, 64), 256, 0, stream>>>(u, Uny);

  // G1: Auf = bf16(Wdft_gen @ u), 256 blocks, ks2 bf16 partials + add-cast
  gemmG<0><<<256, 512, 0, stream>>>(uT, LSEQ, G1P, nullptr);
  add2_cast<<<dim3(MR * DDIM / 2048), 256, 0, stream>>>(G1P, Auf);

  // G2: 8 XCD-combo slots (full coverage, no memset); 1024-thread 16-wave build
  gemmW<<<256, 1024, 0, stream>>>(Auf, Mt, Pw, Slots);

  // Ybt = bf16((sum of 4 jg-slots)^T); Nyquist vector (needs Mt) before G3
  tr_reduce4<<<dim3(16, 256), 256, 0, stream>>>(Slots, Ybt);
  hipMemsetAsync(vny, 0, DDIM * sizeof(float), stream);
  vnyq_k<<<dim3(48, 4), 256, 0, stream>>>(Mt, Uny, wny, vny);

  // G3: y = Cinv_gen @ Ysum via 4 f32 ksplit partials + fused Nyquist reduce
  gemmG<1><<<256, 512, 0, stream>>>(Ybt, MR, nullptr, G3P);
  reduce4y<<<dim3(LSEQ * DDIM / 1024), 256, 0, stream>>>(G3P, vny, y);
}

// Round 13
// 477.385 us; speedup vs baseline: 1.0611x; 1.0144x over previous
//
#include <hip/hip_runtime.h>
#include <hip/hip_bf16.h>
#include <cstdint>
#include <cstddef>

using bf16 = __hip_bfloat16;

typedef __attribute__((ext_vector_type(4))) float f32x4;
typedef __attribute__((ext_vector_type(8))) short s16x8;

#define LSEQ 4096
#define DDIM 512
#define KFLT 24
#define NFFT 8192
#define MR 8192              // 2*4096 interleaved re/im rows (Nyquist handled rank-1)

__device__ __forceinline__ void gld16(const bf16* g, bf16* l) {
  __builtin_amdgcn_global_load_lds((const __attribute__((address_space(1))) void*)g,
                                   (__attribute__((address_space(3))) void*)l, 16, 0, 0);
}

#define MEMFENCE asm volatile("" ::: "memory")
#define BAR() do { MEMFENCE; __builtin_amdgcn_s_barrier(); MEMFENCE; } while (0)

__device__ __forceinline__ float fsin_rev(float rev) {
  float s; asm("v_sin_f32 %0, %1" : "=v"(s) : "v"(rev)); return s;
}
__device__ __forceinline__ float fcos_rev(float rev) {
  float c; asm("v_cos_f32 %0, %1" : "=v"(c) : "v"(rev)); return c;
}

// Stage one 128x64 half-tile with 16 waves x 1 chunk (1024-thr blocks)
__device__ __forceinline__ void stage16(const bf16* g, int ldk, bf16* ldsbase,
                                        int wave, int lane) {
  const int r8 = lane >> 3;
  const int sc = ((lane & 7) ^ r8) * 8;
  gld16(g + (size_t)(wave * 8 + r8) * ldk + sc, ldsbase + wave * 512);
}

// swizzled LDS fragment read: 16B at slot (kk*4+l4)^(row&7)
__device__ __forceinline__ s16x8 ldfrag(const bf16* buf, int row, int kk, int l4) {
  return *(const s16x8*)(buf + row * 64 + (((kk * 4 + l4) ^ (row & 7)) * 8));
}

// -------- transpose + cast->bf16: out[c][r] = bf16(in[r][c]), batched over z
__global__ __launch_bounds__(256) void transpose_cast(
    const float* __restrict__ in, bf16* __restrict__ out, int R, int C) {
  __shared__ float tile[32][33];
  const size_t bo = (size_t)blockIdx.z * R * C;
  const float* inb = in + bo;
  bf16* outb = out + bo;
  int c0 = blockIdx.x * 32, r0 = blockIdx.y * 32;
  int tx = threadIdx.x & 31, ty = threadIdx.x >> 5;
  #pragma unroll
  for (int i = 0; i < 32; i += 8)
    tile[ty + i][tx] = inb[(size_t)(r0 + ty + i) * C + (c0 + tx)];
  __syncthreads();
  #pragma unroll
  for (int i = 0; i < 32; i += 8)
    outb[(size_t)(c0 + ty + i) * R + (r0 + tx)] = __float2bfloat16(tile[tx][ty + i]);
}

// -------- Auf = bf16(P0 + P1) (two bf16 half-K partials)
__global__ __launch_bounds__(256) void add2_cast(
    const bf16* __restrict__ P, bf16* __restrict__ out) {
  size_t i = ((size_t)blockIdx.x * 256 + threadIdx.x) * 8;
  const size_t MN = (size_t)MR * DDIM;
  s16x8 a = *(const s16x8*)(P + i);
  s16x8 b = *(const s16x8*)(P + i + MN);
  bf16 o[8];
  #pragma unroll
  for (int e = 0; e < 8; ++e) {
    float fa = __uint_as_float((unsigned)(unsigned short)a[e] << 16);
    float fb = __uint_as_float((unsigned)(unsigned short)b[e] << 16);
    o[e] = __float2bfloat16(fa + fb);
  }
  *(s16x8*)(out + i) = *(const s16x8*)o;
}

// -------- Ybt[c][r] = bf16(sum_jg Slot[(jg,nt(c))][r][c&255]); slots [8192][256] f32
__global__ __launch_bounds__(256) void tr_reduce4(
    const float* __restrict__ S, bf16* __restrict__ out) {
  __shared__ float tile[32][33];
  int c0 = blockIdx.x * 32, r0 = blockIdx.y * 32;
  int tx = threadIdx.x & 31, ty = threadIdx.x >> 5;
  const int nt = c0 >> 8;
  const int scl = (c0 & 255) + tx;
  const size_t SB = (size_t)MR * 256;
  #pragma unroll
  for (int i = 0; i < 32; i += 8) {
    size_t ro = (size_t)(r0 + ty + i) * 256 + scl;
    tile[ty + i][tx] = S[(0 * 2 + nt) * SB + ro] + S[(1 * 2 + nt) * SB + ro] +
                       S[(2 * 2 + nt) * SB + ro] + S[(3 * 2 + nt) * SB + ro];
  }
  __syncthreads();
  #pragma unroll
  for (int i = 0; i < 32; i += 8)
    out[(size_t)(c0 + ty + i) * MR + (r0 + tx)] = __float2bfloat16(tile[tx][ty + i]);
}

// -------- y = sum of 4 f32 partials + (-1)^l * vnyq[o] / NFFT
__global__ __launch_bounds__(256) void reduce4y(
    const float* __restrict__ P, const float* __restrict__ vnyq,
    float* __restrict__ y) {
  size_t i = ((size_t)blockIdx.x * 256 + threadIdx.x) * 4;
  const size_t MN = (size_t)LSEQ * DDIM;
  int l = (int)(i >> 9), o = (int)(i & 511);
  f32x4 a = *(const f32x4*)(P + i);
  f32x4 b = *(const f32x4*)(P + i + MN);
  f32x4 c = *(const f32x4*)(P + i + 2 * MN);
  f32x4 d = *(const f32x4*)(P + i + 3 * MN);
  f32x4 v = *(const f32x4*)(vnyq + o);
  float sg = (l & 1) ? -(1.f / NFFT) : (1.f / NFFT);
  f32x4 r = a + b + c + d;
  r[0] += sg * v[0]; r[1] += sg * v[1]; r[2] += sg * v[2]; r[3] += sg * v[3];
  *(f32x4*)(y + i) = r;
}

// -------- Pf[f][k][re,im] f32, f in [0,4096]; 2 f per block (phi reads amortized)
__global__ __launch_bounds__(256) void compute_pf(
    const float* __restrict__ phi, float* __restrict__ Pf) {
  int f0 = blockIdx.x * 2;
  int tid = threadIdx.x;
  int lane = tid & 63, wave = tid >> 6;
  float pre[2][KFLT], pim[2][KFLT];
  #pragma unroll
  for (int ff = 0; ff < 2; ++ff)
    #pragma unroll
    for (int k = 0; k < KFLT; ++k) { pre[ff][k] = 0.f; pim[ff][k] = 0.f; }
  for (int cch = 0; cch < LSEQ / 256; ++cch) {
    int t = cch * 256 + tid;
    const float4* pv = (const float4*)(phi + (size_t)t * KFLT);
    float4 v0 = pv[0], v1 = pv[1], v2 = pv[2], v3 = pv[3], v4 = pv[4], v5 = pv[5];
    float pr[KFLT] = {v0.x, v0.y, v0.z, v0.w, v1.x, v1.y, v1.z, v1.w,
                      v2.x, v2.y, v2.z, v2.w, v3.x, v3.y, v3.z, v3.w,
                      v4.x, v4.y, v4.z, v4.w, v5.x, v5.y, v5.z, v5.w};
    #pragma unroll
    for (int ff = 0; ff < 2; ++ff) {
      int m = ((f0 + ff) * t) & (NFFT - 1);
      float rev = (float)m * (1.f / NFFT);
      float s = fsin_rev(rev), c = fcos_rev(rev);
      #pragma unroll
      for (int k = 0; k < KFLT; ++k) {
        pre[ff][k] += pr[k] * c;
        pim[ff][k] -= pr[k] * s;
      }
    }
  }
  __shared__ float red[4][2][2 * KFLT];
  #pragma unroll
  for (int ff = 0; ff < 2; ++ff)
    #pragma unroll
    for (int k = 0; k < KFLT; ++k) {
      float r = pre[ff][k], i2 = pim[ff][k];
      #pragma unroll
      for (int off = 32; off > 0; off >>= 1) {
        r += __shfl_down(r, off, 64);
        i2 += __shfl_down(i2, off, 64);
      }
      if (lane == 0) { red[wave][ff][2 * k] = r; red[wave][ff][2 * k + 1] = i2; }
    }
  __syncthreads();
  if (tid < 96) {
    int ff = tid / 48, q = tid % 48;
    int f = f0 + ff;
    if (f <= NFFT / 2)
      Pf[(size_t)f * 48 + q] =
          red[0][ff][q] + red[1][ff][q] + red[2][ff][q] + red[3][ff][q];
  }
}

// -------- Pw[j][f][re,im], f in [0,4096); also wnyq[48]
__global__ __launch_bounds__(256) void build_pw(
    const float* __restrict__ Pf, float* __restrict__ Pw, float* __restrict__ wnyq) {
  int idx = blockIdx.x * 256 + threadIdx.x;
  int j = idx >> 12, f = idx & 4095;
  float re, im;
  if (j < KFLT) {
    re = Pf[(size_t)f * 48 + j * 2];
    im = Pf[(size_t)f * 48 + j * 2 + 1];
  } else {
    int k = j - KFLT, g = NFFT / 2 - f;
    re = Pf[(size_t)g * 48 + k * 2];
    im = -Pf[(size_t)g * 48 + k * 2 + 1];
  }
  Pw[(size_t)idx * 2] = re;
  Pw[(size_t)idx * 2 + 1] = im;
  if (idx < 48)
    wnyq[idx] = (idx < KFLT) ? Pf[(size_t)(NFFT / 2) * 48 + idx * 2]
                             : Pf[(idx - KFLT) * 2];
}

// -------- Unyq[d] += partial sum_t (-1)^t u[t][d]  (coalesced, 128 blocks)
__global__ __launch_bounds__(256) void nyq_u(
    const float* __restrict__ u, float* __restrict__ Unyq) {
  int d = blockIdx.x * 256 + threadIdx.x;
  int t0 = blockIdx.y * 64;
  float acc = 0.f;
  for (int t = t0; t < t0 + 64; t += 2)
    acc += u[(size_t)t * DDIM + d] - u[(size_t)(t + 1) * DDIM + d];
  atomicAdd(&Unyq[d], acc);
}

// -------- vnyq[o] += wnyq[j] * sum_d Unyq[d]*Mt[j][o][d]   (grid 48 x 4)
__global__ __launch_bounds__(256) void vnyq_k(
    const bf16* __restrict__ Mt, const float* __restrict__ Unyq,
    const float* __restrict__ wnyq, float* __restrict__ vnyq) {
  __shared__ float us[DDIM];
  int j = blockIdx.x, tid = threadIdx.x;
  us[tid] = Unyq[tid];
  us[tid + 256] = Unyq[tid + 256];
  __syncthreads();
  float w = wnyq[j];
  int o = blockIdx.y * 128 + (tid >> 1);
  int dh = (tid & 1) * 256;
  const bf16* row = Mt + ((size_t)j * DDIM + o) * DDIM + dh;
  float acc = 0.f;
  for (int d0 = 0; d0 < 256; d0 += 8) {
    s16x8 v = *(const s16x8*)(row + d0);
    #pragma unroll
    for (int e = 0; e < 8; ++e)
      acc += us[dh + d0 + e] * __uint_as_float((unsigned)(unsigned short)v[e] << 16);
  }
  acc += __shfl_xor(acc, 1, 64);
  if ((tid & 1) == 0) atomicAdd(&vnyq[o], w * acc);
}

// ======== GEN-GEMM (G1/G3): C = Wgen[M,K] @ Bt[N,K]^T, BM=128 BN=256 BK=64.
// 16-WAVE OCCUPANCY BUILD (R12 gemmW cure applied): 1024 threads, 4 waves/SIMD,
// wave = 32x64 (acc[2][4] = 32 VGPR). A-tile generated in-kernel (trig, 8 sincos
// per thread per unit), swizzled ds_write; B staged via stage16 (counted vmcnt(2)).
// Same genA expressions + per-element MFMA order as R12 -> bit-identical output.
// STORE 0 (G1, fwd-DFT rows): ks2 x mt64 x nt2; bf16 partial store.
// STORE 1 (G3, inv-DFT rows): ks4 x mt32 x nt2; f32 partial store.
template <int STORE>
__global__ __launch_bounds__(1024, 4) void gemmG(
    const bf16* __restrict__ Bt, int ldk,
    bf16* __restrict__ Obf, float* __restrict__ Of) {
  __shared__ bf16 sA[3 * 128 * 64];
  __shared__ bf16 sB[3 * 256 * 64];

  const int lin = blockIdx.x;
  const int wid = (lin & 7) * 32 + (lin >> 3);

  int mt, nt, kt0, nkt, ks;
  if constexpr (STORE == 0) {
    ks = wid >> 7; int rem = wid & 127; mt = rem >> 1; nt = rem & 1;
    kt0 = ks * 32; nkt = 32;
  } else {
    ks = wid >> 6; int rem = wid & 63; mt = rem >> 1; nt = rem & 1;
    kt0 = ks * 32; nkt = 32;
  }

  const int tid = threadIdx.x, lane = tid & 63, wave = tid >> 6;  // 0..15
  const int l15 = lane & 15, l4 = lane >> 4;
  const int wr = wave >> 2, wc = wave & 3;   // 4x4 waves: wave = 32 x 64
  const int r8 = lane >> 3, c8 = lane & 7;
  const int mtile = mt * 128, ntile = nt * 256;
  const bf16* Bb = Bt + (size_t)ntile * ldk;

  f32x4 acc[2][4];
  #pragma unroll
  for (int m = 0; m < 2; ++m)
    #pragma unroll
    for (int n = 0; n < 4; ++n) acc[m][n] = f32x4{0.f, 0.f, 0.f, 0.f};

  // generate this thread's 8 A elements for K-unit t into LDS buf (swizzled);
  // 16 waves cover the 128x64 tile (chunk = wave)
  auto genA = [&](int t, int buf) {
    const int kbase = (kt0 + t) * 64 + ((c8 ^ r8) * 8);   // pre-swizzled col base
    const int row = mtile + wave * 8 + r8;
    bf16 o[8];
    if constexpr (STORE == 0) {
      const int f = row >> 1;
      const bool odd = row & 1;
      #pragma unroll
      for (int e = 0; e < 8; ++e) {
        int m = (f * (kbase + e)) & (NFFT - 1);
        float rev = (float)m * (1.f / NFFT);
        o[e] = __float2bfloat16(odd ? -fsin_rev(rev) : fcos_rev(rev));
      }
    } else {
      #pragma unroll
      for (int e = 0; e < 8; ++e) {
        int r = kbase + e;
        int f = r >> 1;
        int m = (f * row) & (NFFT - 1);
        float rev = (float)m * (1.f / NFFT);
        float sc2 = ((f == 0) ? 1.f : 2.f) * (1.f / NFFT);
        o[e] = __float2bfloat16((r & 1) ? -sc2 * fsin_rev(rev)
                                        : sc2 * fcos_rev(rev));
      }
    }
    *(s16x8*)(sA + buf * (128 * 64) + (wave * 8 + r8) * 64 + c8 * 8) =
        *(const s16x8*)o;
  };
  auto stageB = [&](int t, int buf) {
    const size_t ko = (size_t)(kt0 + t) * 64;
    stage16(Bb + ko, ldk, sB + buf * (256 * 64), wave, lane);
    stage16(Bb + (size_t)128 * ldk + ko, ldk, sB + buf * (256 * 64) + 128 * 64,
            wave, lane);
  };

  genA(0, 0);
  genA(1, 1);
  stageB(0, 0);
  stageB(1, 1);
  asm volatile("s_waitcnt vmcnt(2)" ::: "memory");   // B(0) landed, B(1) in flight
  asm volatile("s_waitcnt lgkmcnt(0)" ::: "memory"); // A(0),A(1) writes done
  BAR();

  for (int t = 0; t < nkt; ++t) {
    const int buf = t % 3;
    const bf16* bA = sA + buf * (128 * 64);
    const bf16* bB = sB + buf * (256 * 64);
    const bool i2 = (t + 2 < nkt);

    s16x8 afr[2][2], bfr[4][2];
    #pragma unroll
    for (int n = 0; n < 4; ++n)
      #pragma unroll
      for (int kk = 0; kk < 2; ++kk)
        bfr[n][kk] = ldfrag(bB, wc * 64 + n * 16 + l15, kk, l4);
    #pragma unroll
    for (int m = 0; m < 2; ++m)
      #pragma unroll
      for (int kk = 0; kk < 2; ++kk)
        afr[m][kk] = ldfrag(bA, wr * 32 + m * 16 + l15, kk, l4);

    if (i2) {
      genA(t + 2, (t + 2) % 3);
      stageB(t + 2, (t + 2) % 3);
    }

    __builtin_amdgcn_s_setprio(1);
    #pragma unroll
    for (int m = 0; m < 2; ++m)
      #pragma unroll
      for (int n = 0; n < 4; ++n)
        #pragma unroll
        for (int kk = 0; kk < 2; ++kk)
          acc[m][n] = __builtin_amdgcn_mfma_f32_16x16x32_bf16(
              afr[m][kk], bfr[n][kk], acc[m][n], 0, 0, 0);
    __builtin_amdgcn_s_setprio(0);

    if (i2) { asm volatile("s_waitcnt vmcnt(2)" ::: "memory"); }
    else    { asm volatile("s_waitcnt vmcnt(0)" ::: "memory"); }
    asm volatile("s_waitcnt lgkmcnt(0)" ::: "memory");
    BAR();
  }

  #pragma unroll
  for (int m = 0; m < 2; ++m)
    #pragma unroll
    for (int n = 0; n < 4; ++n)
      #pragma unroll
      for (int e = 0; e < 4; ++e) {
        int row = mtile + wr * 32 + m * 16 + l4 * 4 + e;
        int col = ntile + wc * 64 + n * 16 + l15;
        if constexpr (STORE == 0)
          Obf[(size_t)ks * MR * DDIM + (size_t)row * DDIM + col] =
              __float2bfloat16(acc[m][n][e]);
        else
          Of[(size_t)ks * LSEQ * DDIM + (size_t)row * DDIM + col] = acc[m][n][e];
      }
}

// ======== G2: Slot[(jg,nt)] = sum_{j in jg} Pw[j] .* (Auf @ Mt_j^T).
// 16-WAVE OCCUPANCY BUILD: 1024 threads (4 waves/SIMD), wave = 32x128
// (acc[2][8]=64 regs). Register-resident A per kt; per-j A-frags built
// in-register via quad_perm DPP row-pair mix. B: 3-deep LDS, staged 2-ahead,
// counted vmcnt(2); 1 barrier/unit.
__global__ __launch_bounds__(1024, 4) void gemmW(
    const bf16* __restrict__ Auf, const bf16* __restrict__ Mt,
    const float* __restrict__ Pw, float* __restrict__ Slots) {
  __shared__ bf16 sB[3 * 256 * 64];     // 96KB
  __shared__ bf16 sA[256 * 64];         // 32KB (single buffer, kt granularity)
  __shared__ float2 sW[12 * 128];       // 12KB Pw slice [jj][f-local]

  const int lin = blockIdx.x;
  const int q = lin & 7;                // XCD slot (round-robin dispatch)
  const int pos = lin >> 3;             // 0..31 within XCD
  const int jg = q >> 1, mhalf = q & 1;
  const int nt = pos >> 4;
  const int mt = mhalf * 16 + (pos & 15);

  const int tid = threadIdx.x, lane = tid & 63, wave = tid >> 6;  // 0..15
  const int l15 = lane & 15, l4 = lane >> 4;
  const int wr = wave >> 1, wc = wave & 1;   // 8x2 waves: wave = 32 x 128

  float* dst = Slots + (size_t)(jg * 2 + nt) * ((size_t)MR * 256);

  f32x4 acc[2][8];
  #pragma unroll
  for (int m = 0; m < 2; ++m)
    #pragma unroll
    for (int n = 0; n < 8; ++n) acc[m][n] = f32x4{0.f, 0.f, 0.f, 0.f};

  auto stageB_ = [&](int s) {
    const int j = jg * 12 + (s % 12), kt = s / 12;
    const bf16* bb = Mt + (size_t)j * (DDIM * DDIM) + (size_t)(nt * 256) * DDIM + kt * 64;
    bf16* db = sB + (s % 3) * (256 * 64);
    stage16(bb, DDIM, db, wave, lane);
    stage16(bb + (size_t)128 * DDIM, DDIM, db + 128 * 64, wave, lane);
  };
  auto stageA_ = [&](int kt) {
    const bf16* ab = Auf + (size_t)(mt * 256) * DDIM + kt * 64;
    stage16(ab, DDIM, sA, wave, lane);
    stage16(ab + (size_t)128 * DDIM, DDIM, sA + 128 * 64, wave, lane);
  };

  // ---- prologue: Pw slice -> sW; stage B(0),B(1),A(0); drain once
  for (int idx = tid; idx < 1536; idx += 1024) {
    int jj2 = idx >> 7, fo = idx & 127;
    sW[idx] = *(const float2*)(Pw +
        (((size_t)(jg * 12 + jj2)) * 4096 + (size_t)mt * 128 + fo) * 2);
  }
  stageB_(0);
  stageB_(1);
  stageA_(0);
  asm volatile("s_waitcnt vmcnt(0) lgkmcnt(0)" ::: "memory");
  BAR();

  int4 selfA[2][2];                             // [m][kk], per-kt U-hat frags

  for (int s = 0; s < 96; ++s) {
    const int jj = s % 12, kt = s / 12;
    const bf16* bB = sB + (s % 3) * (256 * 64);

    if (s) {
      if (s == 95) { asm volatile("s_waitcnt vmcnt(0)" ::: "memory"); }
      else         { asm volatile("s_waitcnt vmcnt(2)" ::: "memory"); }
      BAR();
    }
    if (s + 2 < 96) stageB_(s + 2);
    if (jj == 6 && kt < 7) stageA_(kt + 1);

    if (jj == 0) {
      #pragma unroll
      for (int m = 0; m < 2; ++m)
        #pragma unroll
        for (int kk = 0; kk < 2; ++kk) {
          s16x8 v = ldfrag(sA, wr * 32 + m * 16 + l15, kk, l4);
          selfA[m][kk] = *(const int4*)&v;
        }
    }

    float wx[2], swy[2];
    #pragma unroll
    for (int m = 0; m < 2; ++m) {
      int fr = (wr * 32 + m * 16 + l15) >> 1;   // local f index 0..127
      float2 w = sW[jj * 128 + fr];
      wx[m] = w.x;
      swy[m] = (l15 & 1) ? w.y : -w.y;
    }

    #pragma unroll
    for (int kk = 0; kk < 2; ++kk) {
      // build both A-frags for this kk (in-register complex mix)
      s16x8 afr[2];
      #pragma unroll
      for (int m = 0; m < 2; ++m) {
        const int4 sv = selfA[m][kk];
        int4 pv;
        pv.x = __builtin_amdgcn_mov_dpp(sv.x, 0xB1, 0xF, 0xF, true);  // lane^1
        pv.y = __builtin_amdgcn_mov_dpp(sv.y, 0xB1, 0xF, 0xF, true);
        pv.z = __builtin_amdgcn_mov_dpp(sv.z, 0xB1, 0xF, 0xF, true);
        pv.w = __builtin_amdgcn_mov_dpp(sv.w, 0xB1, 0xF, 0xF, true);
        const int sp[4] = {sv.x, sv.y, sv.z, sv.w};
        const int pp[4] = {pv.x, pv.y, pv.z, pv.w};
        bf16 ob[8];
        #pragma unroll
        for (int t2 = 0; t2 < 4; ++t2) {
          float fsl = __uint_as_float((unsigned)sp[t2] << 16);
          float fsh = __uint_as_float((unsigned)sp[t2] & 0xffff0000u);
          float fpl = __uint_as_float((unsigned)pp[t2] << 16);
          float fph = __uint_as_float((unsigned)pp[t2] & 0xffff0000u);
          ob[2 * t2]     = __float2bfloat16(wx[m] * fsl + swy[m] * fpl);
          ob[2 * t2 + 1] = __float2bfloat16(wx[m] * fsh + swy[m] * fph);
        }
        afr[m] = *(const s16x8*)ob;
      }
      // n split in two halves keeps live bfr regs at 4 x s16x8
      #pragma unroll
      for (int nh = 0; nh < 2; ++nh) {
        s16x8 bfr[4];
        #pragma unroll
        for (int n = 0; n < 4; ++n)
          bfr[n] = ldfrag(bB, wc * 128 + (nh * 4 + n) * 16 + l15, kk, l4);
        __builtin_amdgcn_s_setprio(1);
        #pragma unroll
        for (int m = 0; m < 2; ++m)
          #pragma unroll
          for (int n = 0; n < 4; ++n)
            acc[m][nh * 4 + n] = __builtin_amdgcn_mfma_f32_16x16x32_bf16(
                afr[m], bfr[n], acc[m][nh * 4 + n], 0, 0, 0);
        __builtin_amdgcn_s_setprio(0);
      }
    }
  }

  // single flush into the block's private (mt, nt) slot region
  #pragma unroll
  for (int m = 0; m < 2; ++m)
    #pragma unroll
    for (int n = 0; n < 8; ++n)
      #pragma unroll
      for (int e = 0; e < 4; ++e) {
        int row = mt * 256 + wr * 32 + m * 16 + l4 * 4 + e;
        int col = wc * 128 + n * 16 + l15;
        dst[(size_t)row * 256 + col] = acc[m][n][e];
      }
}

// ---------------- workspace layout (bytes) ----------------
#define WS_W     0ULL                    // 67,108,864: G2 slots (8 x [8192][256] f32)
#define WS_AUF   67108864ULL             // 8192x512 bf16 = 8,388,608 (later G3P start)
#define WS_UT    75497472ULL             // 512x4096 bf16 = 4,194,304
#define WS_MT    79691776ULL             // 48x512x512 bf16 = 25,165,824
#define WS_PF    104857600ULL            // 4097x48 f32
#define WS_PW    105644288ULL            // 48x4096x2 f32 = 1,572,864
#define WS_WNYQ  107217152ULL            // 48 f32
#define WS_UNYQ  107217408ULL            // 512 f32
#define WS_VNYQ  107219456ULL            // 512 f32
#define WS_YBT   107221504ULL            // 512x8192 bf16 = 8,388,608
#define WS_G1P   115610112ULL            // 2 x 8192x512 bf16 = 16,777,216
#define WS_TOTAL 132387328ULL
// G3 partials: 4 x 4096x512 f32 = 33,554,432 at WS_AUF (Auf/uT/Mt dead by G3)

extern "C" void kernel_launch(void* const* d_in, const int* in_sizes, int n_in,
                              void* d_out, int out_size, void* d_ws, size_t ws_size,
                              hipStream_t stream) {
  const float* u   = (const float*)d_in[0];   // [4096, 512]
  const float* phi = (const float*)d_in[1];   // [4096, 24]
  const float* Mp  = (const float*)d_in[2];   // [24, 512, 512]
  const float* Mm  = (const float*)d_in[3];   // [24, 512, 512]
  float* y = (float*)d_out;                   // [4096, 512]

  if (ws_size < WS_TOTAL) return;             // loud failure: output stays zero

  char* ws = (char*)d_ws;
  float* Slots= (float*)(ws + WS_W);
  bf16*  Auf  = (bf16*)(ws + WS_AUF);
  bf16*  uT   = (bf16*)(ws + WS_UT);
  bf16*  Mt   = (bf16*)(ws + WS_MT);
  float* Pf   = (float*)(ws + WS_PF);
  float* Pw   = (float*)(ws + WS_PW);
  float* wny  = (float*)(ws + WS_WNYQ);
  float* Uny  = (float*)(ws + WS_UNYQ);
  float* vny  = (float*)(ws + WS_VNYQ);
  bf16*  Ybt  = (bf16*)(ws + WS_YBT);
  bf16*  G1P  = (bf16*)(ws + WS_G1P);
  float* G3P  = (float*)(ws + WS_AUF);        // G3 partials overlay

  // prologue (no W/Cinv materialization — generated inside gemmG)
  transpose_cast<<<dim3(16, 128, 1), 256, 0, stream>>>(u, uT, LSEQ, DDIM);
  transpose_cast<<<dim3(16, 16, 24), 256, 0, stream>>>(Mp, Mt, DDIM, DDIM);
  transpose_cast<<<dim3(16, 16, 24), 256, 0, stream>>>(Mm, Mt + (size_t)24 * DDIM * DDIM,
                                                       DDIM, DDIM);
  compute_pf<<<dim3(2049), 256, 0, stream>>>(phi, Pf);
  build_pw<<<dim3(48 * 4096 / 256), 256, 0, stream>>>(Pf, Pw, wny);
  hipMemsetAsync(Uny, 0, DDIM * sizeof(float), stream);
  nyq_u<<<dim3(2, 64), 256, 0, stream>>>(u, Uny);

  // G1: Auf = bf16(Wdft_gen @ u), 256 blocks x 1024 thr, ks2 partials + add-cast
  gemmG<0><<<256, 1024, 0, stream>>>(uT, LSEQ, G1P, nullptr);
  add2_cast<<<dim3(MR * DDIM / 2048), 256, 0, stream>>>(G1P, Auf);

  // G2: 8 XCD-combo slots (full coverage, no memset); 1024-thread 16-wave build
  gemmW<<<256, 1024, 0, stream>>>(Auf, Mt, Pw, Slots);

  // Ybt = bf16((sum of 4 jg-slots)^T); Nyquist vector (needs Mt) before G3
  tr_reduce4<<<dim3(16, 256), 256, 0, stream>>>(Slots, Ybt);
  hipMemsetAsync(vny, 0, DDIM * sizeof(float), stream);
  vnyq_k<<<dim3(48, 4), 256, 0, stream>>>(Mt, Uny, wny, vny);

  // G3: y = Cinv_gen @ Ysum via 4 f32 ksplit partials + fused Nyquist reduce
  gemmG<1><<<256, 1024, 0, stream>>>(Ybt, MR, nullptr, G3P);
  reduce4y<<<dim3(LSEQ * DDIM / 1024), 256, 0, stream>>>(G3P, vny, y);
}